// Round 2
// baseline (1362.913 us; speedup 1.0000x reference)
//
#include <hip/hip_runtime.h>
#include <hip/hip_bf16.h>
#include <math.h>

#define BDIM 16384
#define HDIM 512

typedef __bf16 bf16;
typedef float f32x4 __attribute__((ext_vector_type(4)));
typedef __bf16 bf16x8 __attribute__((ext_vector_type(8)));
typedef __bf16 bf16x4 __attribute__((ext_vector_type(4)));

// ---------------------------------------------------------------- utilities

__device__ __forceinline__ void gload16(const bf16* g, bf16* l) {
  // async global->LDS, 16B per lane; LDS dest = wave-uniform base + lane*16
  __builtin_amdgcn_global_load_lds((const __attribute__((address_space(1))) void*)g,
                                   (__attribute__((address_space(3))) void*)l, 16, 0, 0);
}

__device__ __forceinline__ float gelu_exact(float x) {
  return 0.5f * x * (1.0f + erff(x * 0.70710678118654752f));
}

__device__ __forceinline__ float gelu_fast(float x) {
  // tanh approximation: |err| ~1e-3, far below bf16 quantization of the output
  float u = x * (0.7978845608f + 0.0356774081f * x * x);
  float e = __expf(2.f * u);
  float t = 1.f - 2.f / (e + 1.f);
  return 0.5f * x * (1.f + t);
}

// ---------------------------------------------------------------- converts

__global__ void cvt_f32_bf16(const float* __restrict__ src, bf16* __restrict__ dst, int n4) {
  int i = blockIdx.x * blockDim.x + threadIdx.x;
  if (i >= n4) return;
  f32x4 v = *(const f32x4*)(src + (size_t)i * 4);
  bf16x4 o;
  o[0] = (bf16)v[0]; o[1] = (bf16)v[1]; o[2] = (bf16)v[2]; o[3] = (bf16)v[3];
  *(bf16x4*)(dst + (size_t)i * 4) = o;
}

// wvT[il][k][m] = wv[il][m][k]; wv = rows 1024..1535 of qkv block il ([1536][512])
__global__ void cvt_wvT(const float* __restrict__ qkv, bf16* __restrict__ dst) {
  __shared__ float t[32][33];
  int il = blockIdx.z;
  int bm = blockIdx.x * 32;   // source row block (m)
  int bk = blockIdx.y * 32;   // source col block (k)
  const float* s = qkv + (size_t)il * 786432 + 524288;
  int tx = threadIdx.x & 31, ty = threadIdx.x >> 5;  // ty 0..7
#pragma unroll
  for (int j = 0; j < 4; ++j)
    t[ty * 4 + j][tx] = s[(size_t)(bm + ty * 4 + j) * 512 + bk + tx];
  __syncthreads();
  bf16* d = dst + (size_t)il * 262144;
#pragma unroll
  for (int j = 0; j < 4; ++j)
    d[(size_t)(bk + ty * 4 + j) * 512 + bm + tx] = (bf16)t[tx][ty * 4 + j];
}

__global__ void zfill(float* __restrict__ p, int n) {
  int i = blockIdx.x * 256 + threadIdx.x;
  if (i < n) p[i] = 0.f;
}

// bc[il][n] = sum_m ao[il][n][m] * bv[il][m] + aob[il][n]   (f32, one wave per n)
__global__ void bias_combine(const float* __restrict__ aow, const float* __restrict__ qkvb,
                             const float* __restrict__ aob, float* __restrict__ bc) {
  int gid = blockIdx.x * 4 + (threadIdx.x >> 6);   // 0..3071 == il*512+n
  int il = gid >> 9;
  int lane = threadIdx.x & 63;
  const float* ar = aow + (size_t)gid * 512 + lane * 8;
  const float* bv = qkvb + il * 1536 + 1024 + lane * 8;
  float s = 0.f;
#pragma unroll
  for (int i = 0; i < 8; ++i) s += ar[i] * bv[i];
#pragma unroll
  for (int off = 32; off > 0; off >>= 1) s += __shfl_xor(s, off);
  if (lane == 0) bc[gid] = s + aob[gid];
}

// ---------------------------------------------------------------- GEMM 256x256, 8 waves, dbuf 2-phase
// C[M][N] = act(A[M][K] @ W[N][K]^T + bias); z-batched via signed strides.

template<int ACT>   // 0 none, 1 gelu
__launch_bounds__(512, 2)
__global__ void gemm256(const bf16* __restrict__ A, long long Az, int lda,
                        const bf16* __restrict__ W, long long Wz,
                        const float* __restrict__ bias, long long bz,
                        bf16* __restrict__ C, long long Cz, int ldc, int K) {
  __shared__ bf16 As[2][256 * 64];
  __shared__ bf16 Bs[2][256 * 64];
  const long long z = blockIdx.z;
  A += z * Az; W += z * Wz; bias += z * bz; C += z * Cz;

  const int tid = threadIdx.x;
  const int lane = tid & 63;
  const int wid = tid >> 6;
  const int brow = blockIdx.x * 256;
  const int bcol = blockIdx.y * 256;
  const int wm = (wid >> 2) * 128;  // wave row offset
  const int wn = (wid & 3) * 64;    // wave col offset
  const int lr = lane & 15;
  const int kg = lane >> 4;

  f32x4 acc[8][4] = {};

  const bf16* Ab = A + (size_t)(brow + (tid >> 3)) * lda + ((tid & 7) << 3);
  const bf16* Wb = W + (size_t)(bcol + (tid >> 3)) * K + ((tid & 7) << 3);

  auto stage = [&](int buf, int k0) {
#pragma unroll
    for (int j = 0; j < 4; ++j) {
      gload16(Ab + (size_t)j * 64 * lda + k0, &As[buf][j * 4096 + wid * 512]);
      gload16(Wb + (size_t)j * 64 * K + k0, &Bs[buf][j * 4096 + wid * 512]);
    }
  };
  auto compute = [&](int buf) {
#pragma unroll
    for (int kk = 0; kk < 64; kk += 32) {
      bf16x8 b[4];
#pragma unroll
      for (int n = 0; n < 4; ++n)
        b[n] = *(const bf16x8*)(&Bs[buf][(wn + n * 16 + lr) * 64 + kk + kg * 8]);
#pragma unroll
      for (int m = 0; m < 8; ++m) {
        bf16x8 a = *(const bf16x8*)(&As[buf][(wm + m * 16 + lr) * 64 + kk + kg * 8]);
#pragma unroll
        for (int n = 0; n < 4; ++n)
          acc[m][n] = __builtin_amdgcn_mfma_f32_16x16x32_bf16(a, b[n], acc[m][n], 0, 0, 0);
      }
    }
  };

  stage(0, 0);
  __syncthreads();
  const int nt = K >> 6;
  for (int t = 0; t < nt - 1; ++t) {
    stage((t & 1) ^ 1, (t + 1) << 6);   // prefetch next tile (latency hides under compute)
    compute(t & 1);
    __syncthreads();                    // drains prefetch vmcnt + LDS read/write ordering
  }
  compute((nt - 1) & 1);

  // epilogue: D mapping col=lane&15, row=kg*4+j
  float bv[4];
#pragma unroll
  for (int n = 0; n < 4; ++n) bv[n] = bias[bcol + wn + n * 16 + lr];
#pragma unroll
  for (int m = 0; m < 8; ++m) {
    int row = brow + wm + m * 16 + kg * 4;
#pragma unroll
    for (int n = 0; n < 4; ++n) {
      int col = bcol + wn + n * 16 + lr;
#pragma unroll
      for (int j = 0; j < 4; ++j) {
        float v = acc[m][n][j] + bv[n];
        if (ACT == 1) v = gelu_fast(v);
        C[(size_t)(row + j) * ldc + col] = (bf16)v;
      }
    }
  }
}

// ---------------------------------------------------------------- GEMM 128x128 (small shapes: Wc)

__launch_bounds__(256)
__global__ void gemm128(const bf16* __restrict__ A, long long Az, int lda,
                        const bf16* __restrict__ W, long long Wz,
                        const float* __restrict__ bias, long long bz,
                        bf16* __restrict__ C, long long Cz, int ldc, int K) {
  __shared__ bf16 As[128 * 64];
  __shared__ bf16 Bs[128 * 64];
  const long long z = blockIdx.z;
  A += z * Az; W += z * Wz; bias += z * bz; C += z * Cz;
  const int tid = threadIdx.x;
  const int lane = tid & 63;
  const int wid = tid >> 6;
  const int brow = blockIdx.x * 128;
  const int bcol = blockIdx.y * 128;
  const int wr = (wid >> 1) * 64;
  const int wc = (wid & 1) * 64;
  const int lr = lane & 15;
  const int kg = lane >> 4;

  f32x4 acc[4][4] = {};

  const bf16* Abase = A + (size_t)(brow + (tid >> 3)) * lda + ((tid & 7) << 3);
  const bf16* Wbase = W + (size_t)(bcol + (tid >> 3)) * K + ((tid & 7) << 3);
  bf16* AsDst = As + wid * 512;
  bf16* BsDst = Bs + wid * 512;

  for (int k0 = 0; k0 < K; k0 += 64) {
#pragma unroll
    for (int j = 0; j < 4; ++j) {
      gload16(Abase + (size_t)j * 32 * lda + k0, AsDst + j * 2048);
      gload16(Wbase + (size_t)j * 32 * K + k0, BsDst + j * 2048);
    }
    __syncthreads();
#pragma unroll
    for (int kk = 0; kk < 64; kk += 32) {
      bf16x8 a[4], b[4];
#pragma unroll
      for (int m = 0; m < 4; ++m)
        a[m] = *(const bf16x8*)(As + (wr + m * 16 + lr) * 64 + kk + kg * 8);
#pragma unroll
      for (int n = 0; n < 4; ++n)
        b[n] = *(const bf16x8*)(Bs + (wc + n * 16 + lr) * 64 + kk + kg * 8);
#pragma unroll
      for (int m = 0; m < 4; ++m)
#pragma unroll
        for (int n = 0; n < 4; ++n)
          acc[m][n] = __builtin_amdgcn_mfma_f32_16x16x32_bf16(a[m], b[n], acc[m][n], 0, 0, 0);
    }
    __syncthreads();
  }

  float bv[4];
#pragma unroll
  for (int n = 0; n < 4; ++n) bv[n] = bias[bcol + wc + n * 16 + lr];
#pragma unroll
  for (int m = 0; m < 4; ++m) {
    int row = brow + wr + m * 16 + kg * 4;
#pragma unroll
    for (int n = 0; n < 4; ++n) {
      int col = bcol + wc + n * 16 + lr;
#pragma unroll
      for (int j = 0; j < 4; ++j)
        C[(size_t)(row + j) * ldc + col] = (bf16)(acc[m][n][j] + bv[n]);
    }
  }
}

// ---------------------------------------------------------------- add + layernorm (z-batched)
// O = LN(X + R) * g + b over 2B rows of 512; gen = row >> 14

__global__ void add_ln(const bf16* __restrict__ X, const bf16* __restrict__ R,
                       const float* __restrict__ g, const float* __restrict__ b,
                       bf16* __restrict__ O) {
  int lane = threadIdx.x & 63;
  int row = blockIdx.x * 4 + (threadIdx.x >> 6);
  int gen = row >> 14;
  size_t base = (size_t)row * HDIM + lane * 8;
  bf16x8 xv = *(const bf16x8*)(X + base);
  bf16x8 rv = *(const bf16x8*)(R + base);
  float v[8], s = 0.f, sq = 0.f;
#pragma unroll
  for (int i = 0; i < 8; ++i) {
    v[i] = (float)xv[i] + (float)rv[i];
    s += v[i]; sq += v[i] * v[i];
  }
#pragma unroll
  for (int off = 32; off > 0; off >>= 1) {
    s += __shfl_xor(s, off);
    sq += __shfl_xor(sq, off);
  }
  float mean = s * (1.f / HDIM);
  float var = sq * (1.f / HDIM) - mean * mean;
  float rstd = rsqrtf(var + 1e-5f);
  const float* gp = g + gen * 1536 + lane * 8;
  const float* bp = b + gen * 1536 + lane * 8;
  bf16x8 o;
#pragma unroll
  for (int i = 0; i < 8; ++i) o[i] = (bf16)((v[i] - mean) * rstd * gp[i] + bp[i]);
  *(bf16x8*)(O + base) = o;
}

// ---------------------------------------------------------------- prior MLP (tiny)

__global__ void prior_fc1(const float* __restrict__ emb, const float* __restrict__ w1,
                          const float* __restrict__ b1, float* __restrict__ h) {
  int j = blockIdx.x * 4 + (threadIdx.x >> 6);
  int lane = threadIdx.x & 63;
  const float* wr = w1 + (size_t)j * 512 + lane * 8;
  const float* e = emb + lane * 8;
  float s = 0.f;
#pragma unroll
  for (int i = 0; i < 8; ++i) s += e[i] * wr[i];
#pragma unroll
  for (int off = 32; off > 0; off >>= 1) s += __shfl_xor(s, off);
  if (lane == 0) h[j] = gelu_exact(s + b1[j]);
}

__global__ void prior_fc2(const float* __restrict__ h, const float* __restrict__ w2,
                          const float* __restrict__ b2, float* __restrict__ p) {
  int j = blockIdx.x * 4 + (threadIdx.x >> 6);
  int lane = threadIdx.x & 63;
  const float* wr = w2 + (size_t)j * 1024 + lane * 16;
  const float* e = h + lane * 16;
  float s = 0.f;
#pragma unroll
  for (int i = 0; i < 16; ++i) s += e[i] * wr[i];
#pragma unroll
  for (int off = 32; off > 0; off >>= 1) s += __shfl_xor(s, off);
  if (lane == 0) p[j] = s + b2[j];
}

// ---------------------------------------------------------------- final select/blend

__global__ void combine(const float* __restrict__ img, const float* __restrict__ txt,
                        const bf16* __restrict__ gen_t, const bf16* __restrict__ gen_i,
                        const float* __restrict__ prior, const int* __restrict__ mt,
                        const float* __restrict__ rw, float* __restrict__ out) {
  int i4 = blockIdx.x * blockDim.x + threadIdx.x;
  if (i4 >= BDIM * 128) return;
  int bb = i4 >> 7;
  int c = (i4 & 127) << 2;
  size_t idx = (size_t)bb * HDIM + c;
  int m = mt[bb];
  f32x4 iv = *(const f32x4*)(img + idx);
  f32x4 tv = *(const f32x4*)(txt + idx);
  f32x4 oi = iv, ot = tv;
  if (m == 2) {
    float r = rw[1];
    bf16x4 gv = *(const bf16x4*)(gen_i + idx);
#pragma unroll
    for (int k = 0; k < 4; ++k) oi[k] = r * iv[k] + (1.f - r) * (float)gv[k];
  } else if (m == 3) {
    oi = *(const f32x4*)(prior + c);
  }
  if (m == 1) {
    float r = rw[0];
    bf16x4 gv = *(const bf16x4*)(gen_t + idx);
#pragma unroll
    for (int k = 0; k < 4; ++k) ot[k] = r * tv[k] + (1.f - r) * (float)gv[k];
  } else if (m == 3) {
    ot = *(const f32x4*)(prior + 512 + c);
  }
  *(f32x4*)(out + idx) = oi;
  *(f32x4*)(out + (size_t)BDIM * HDIM + idx) = ot;
}

// ---------------------------------------------------------------- launch

extern "C" void kernel_launch(void* const* d_in, const int* in_sizes, int n_in,
                              void* d_out, int out_size, void* d_ws, size_t ws_size,
                              hipStream_t stream) {
  const float* img  = (const float*)d_in[0];
  const float* txt  = (const float*)d_in[1];
  const float* ipw  = (const float*)d_in[2];
  const float* ipb  = (const float*)d_in[3];
  const float* qkvw = (const float*)d_in[4];
  const float* qkvb = (const float*)d_in[5];
  const float* aow  = (const float*)d_in[6];
  const float* aob  = (const float*)d_in[7];
  const float* ln1g = (const float*)d_in[8];
  const float* ln1b = (const float*)d_in[9];
  const float* ln2g = (const float*)d_in[10];
  const float* ln2b = (const float*)d_in[11];
  const float* f1w  = (const float*)d_in[12];
  const float* f1b  = (const float*)d_in[13];
  const float* f2w  = (const float*)d_in[14];
  const float* f2b  = (const float*)d_in[15];
  const float* opw  = (const float*)d_in[16];
  const float* opb  = (const float*)d_in[17];
  const float* rw   = (const float*)d_in[18];
  const float* pw1  = (const float*)d_in[19];
  const float* pb1  = (const float*)d_in[20];
  const float* pw2  = (const float*)d_in[21];
  const float* pb2  = (const float*)d_in[22];
  const float* pemb = (const float*)d_in[23];
  const int*   mt   = (const int*)d_in[24];
  float* out = (float*)d_out;

  const size_t B = BDIM;
  char* ws = (char*)d_ws;
  size_t off = 0;
  auto alloc = [&](size_t bytes) -> char* {
    char* p = ws + off;
    off += (bytes + 255) & ~(size_t)255;
    return p;
  };
  bf16* src_bf = (bf16*)alloc(2 * B * 512 * 2);          // [0]=img, [1]=txt
  bf16* ipw_bf = (bf16*)alloc((size_t)2 * 262144 * 2);
  bf16* wvT_bf = (bf16*)alloc((size_t)6 * 262144 * 2);
  bf16* ao_bf  = (bf16*)alloc((size_t)6 * 262144 * 2);
  bf16* f1_bf  = (bf16*)alloc((size_t)6 * 1048576 * 2);
  bf16* f2_bf  = (bf16*)alloc((size_t)6 * 1048576 * 2);
  bf16* op_bf  = (bf16*)alloc((size_t)2 * 262144 * 2);
  bf16* Wc_bf  = (bf16*)alloc((size_t)6 * 262144 * 2);
  float* bc    = (float*)alloc(6 * 512 * 4);
  float* zeros = (float*)alloc(512 * 4);
  float* ph    = (float*)alloc(1024 * 4);
  float* pout  = (float*)alloc(1024 * 4);
  bf16* x      = (bf16*)alloc(2 * B * 512 * 2);
  bf16* xn     = (bf16*)alloc(2 * B * 512 * 2);

  // big path: batched FFN needs h[2][B][2048] bf16 in ws
  bool big = (off + (size_t)2 * B * 2048 * 2 + 4096) <= ws_size;
  bf16* h;
  bf16* attnC;   // attn output / gen output buffer
  if (big) {
    h = (bf16*)alloc((size_t)2 * B * 2048 * 2);
    attnC = h;                       // attn/gen live only when h is otherwise dead
  } else {
    attnC = (bf16*)alloc(2 * B * 512 * 2);
    h = (bf16*)d_out;                // exactly B*2048 bf16; overwritten by combine at the end
  }

  auto cvt = [&](const float* s, bf16* d, size_t n) {
    int n4 = (int)(n / 4);
    cvt_f32_bf16<<<(n4 + 255) / 256, 256, 0, stream>>>(s, d, n4);
  };
  cvt(img, src_bf, B * 512);
  cvt(txt, src_bf + B * 512, B * 512);
  cvt(ipw, ipw_bf, 2 * 262144);
  cvt(aow, ao_bf, 6 * 262144);
  cvt(f1w, f1_bf, 6 * 1048576);
  cvt(f2w, f2_bf, 6 * 1048576);
  cvt(opw, op_bf, 2 * 262144);
  cvt_wvT<<<dim3(16, 16, 6), 256, 0, stream>>>(qkvw, wvT_bf);
  zfill<<<2, 256, 0, stream>>>(zeros, 512);
  bias_combine<<<768, 256, 0, stream>>>(aow, qkvb, aob, bc);

  // Wc[il] = ao[il] @ wv[il]  (A=ao, W=wvT, C=A@W^T)
  gemm128<<<dim3(4, 4, 6), 256, 0, stream>>>(ao_bf, 262144, 512, wvT_bf, 262144,
                                             zeros, 0, Wc_bf, 262144, 512, 512);

  const long long BS = (long long)B * 512;
  // input proj: x = src @ ipw^T + ipb
  gemm256<0><<<dim3(64, 2, 2), 512, 0, stream>>>(src_bf, BS, 512, ipw_bf, 262144,
                                                 ipb, 512, x, BS, 512, 512);

  for (int l = 0; l < 3; ++l) {
    // attn = tgt @ Wc_l^T + bc_l   (tgt: z=0 -> txt, z=1 -> img)
    gemm256<0><<<dim3(64, 2, 2), 512, 0, stream>>>(src_bf + BS, -BS, 512,
                                                   Wc_bf + (size_t)l * 262144, 786432,
                                                   bc + l * 512, 1536, attnC, BS, 512, 512);
    add_ln<<<2 * BDIM / 4, 256, 0, stream>>>(x, attnC, ln1g + l * 512, ln1b + l * 512, xn);
    if (big) {
      gemm256<1><<<dim3(64, 8, 2), 512, 0, stream>>>(xn, BS, 512,
                                                     f1_bf + (size_t)l * 1048576, 3145728,
                                                     f1b + l * 2048, 6144, h, (long long)B * 2048, 2048, 512);
      gemm256<0><<<dim3(64, 2, 2), 512, 0, stream>>>(h, (long long)B * 2048, 2048,
                                                     f2_bf + (size_t)l * 1048576, 3145728,
                                                     f2b + l * 512, 1536, x, BS, 512, 2048);
    } else {
      for (int i = 0; i < 2; ++i) {
        size_t il = (size_t)i * 3 + l;
        gemm256<1><<<dim3(64, 8, 1), 512, 0, stream>>>(xn + (size_t)i * BS, 0, 512,
                                                       f1_bf + il * 1048576, 0,
                                                       f1b + il * 2048, 0, h, 0, 2048, 512);
        gemm256<0><<<dim3(64, 2, 1), 512, 0, stream>>>(h, 0, 2048,
                                                       f2_bf + il * 1048576, 0,
                                                       f2b + il * 512, 0, x + (size_t)i * BS, 0, 512, 2048);
      }
    }
    add_ln<<<2 * BDIM / 4, 256, 0, stream>>>(xn, x, ln2g + l * 512, ln2b + l * 512, x);
  }

  // gen = x @ opw^T + opb  (z=0 -> gen_text, z=1 -> gen_img)
  gemm256<0><<<dim3(64, 2, 2), 512, 0, stream>>>(x, BS, 512, op_bf, 262144,
                                                 opb, 512, attnC, BS, 512, 512);

  prior_fc1<<<256, 256, 0, stream>>>(pemb, pw1, pb1, ph);
  prior_fc2<<<256, 256, 0, stream>>>(ph, pw2, pb2, pout);

  combine<<<(BDIM * 128 + 255) / 256, 256, 0, stream>>>(img, txt, attnC, attnC + BS,
                                                        pout, mt, rw, out);
}

// Round 3
// 1199.646 us; speedup vs baseline: 1.1361x; 1.1361x over previous
//
#include <hip/hip_runtime.h>
#include <hip/hip_bf16.h>
#include <math.h>

#define BDIM 16384
#define HDIM 512

typedef __bf16 bf16;
typedef float f32x4 __attribute__((ext_vector_type(4)));
typedef __bf16 bf16x8 __attribute__((ext_vector_type(8)));
typedef __bf16 bf16x4 __attribute__((ext_vector_type(4)));

// ---------------------------------------------------------------- utilities

__device__ __forceinline__ void gload16(const bf16* g, bf16* l) {
  __builtin_amdgcn_global_load_lds((const __attribute__((address_space(1))) void*)g,
                                   (__attribute__((address_space(3))) void*)l, 16, 0, 0);
}
__device__ __forceinline__ void gload4(const bf16* g, bf16* l) {
  __builtin_amdgcn_global_load_lds((const __attribute__((address_space(1))) void*)g,
                                   (__attribute__((address_space(3))) void*)l, 4, 0, 0);
}

__device__ __forceinline__ float gelu_exact(float x) {
  return 0.5f * x * (1.0f + erff(x * 0.70710678118654752f));
}
__device__ __forceinline__ float gelu_fast(float x) {
  float u = x * (0.7978845608f + 0.0356774081f * x * x);
  float e = __expf(2.f * u);
  float t = 1.f - 2.f / (e + 1.f);
  return 0.5f * x * (1.f + t);
}

// swizzled LDS element offset within a [rows][32] bf16 tile (row stride 64B, 4 16B slots)
__device__ __forceinline__ int lds_off(int r, int kg) {
  return (r << 5) + ((kg ^ ((r >> 1) & 3)) << 3);
}

// ---------------------------------------------------------------- converts

__global__ void cvt_f32_bf16(const float* __restrict__ src, bf16* __restrict__ dst, int n4) {
  int i = blockIdx.x * blockDim.x + threadIdx.x;
  if (i >= n4) return;
  f32x4 v = *(const f32x4*)(src + (size_t)i * 4);
  bf16x4 o;
  o[0] = (bf16)v[0]; o[1] = (bf16)v[1]; o[2] = (bf16)v[2]; o[3] = (bf16)v[3];
  *(bf16x4*)(dst + (size_t)i * 4) = o;
}

// wvT[il][k][m] = wv[il][m][k]; wv = rows 1024..1535 of qkv block il ([1536][512])
__global__ void cvt_wvT(const float* __restrict__ qkv, bf16* __restrict__ dst) {
  __shared__ float t[32][33];
  int il = blockIdx.z;
  int bm = blockIdx.x * 32;
  int bk = blockIdx.y * 32;
  const float* s = qkv + (size_t)il * 786432 + 524288;
  int tx = threadIdx.x & 31, ty = threadIdx.x >> 5;
#pragma unroll
  for (int j = 0; j < 4; ++j)
    t[ty * 4 + j][tx] = s[(size_t)(bm + ty * 4 + j) * 512 + bk + tx];
  __syncthreads();
  bf16* d = dst + (size_t)il * 262144;
#pragma unroll
  for (int j = 0; j < 4; ++j)
    d[(size_t)(bk + ty * 4 + j) * 512 + bm + tx] = (bf16)t[tx][ty * 4 + j];
}

__global__ void zfill(float* __restrict__ p, int n) {
  int i = blockIdx.x * 256 + threadIdx.x;
  if (i < n) p[i] = 0.f;
}

// bc[il][n] = sum_m ao[il][n][m] * bv[il][m] + aob[il][n]
__global__ void bias_combine(const float* __restrict__ aow, const float* __restrict__ qkvb,
                             const float* __restrict__ aob, float* __restrict__ bc) {
  int gid = blockIdx.x * 4 + (threadIdx.x >> 6);
  int il = gid >> 9;
  int lane = threadIdx.x & 63;
  const float* ar = aow + (size_t)gid * 512 + lane * 8;
  const float* bv = qkvb + il * 1536 + 1024 + lane * 8;
  float s = 0.f;
#pragma unroll
  for (int i = 0; i < 8; ++i) s += ar[i] * bv[i];
#pragma unroll
  for (int off = 32; off > 0; off >>= 1) s += __shfl_xor(s, off);
  if (lane == 0) bc[gid] = s + aob[gid];
}

// ---------------------------------------------------------------- main GEMM
// 128x256 tile, BK=32, 4 waves (1Mx4N), dbuf LDS 48KiB -> 3 blocks/CU,
// counted-vmcnt pipeline + T2 swizzle + T5 setprio.
// C[M][N] = act(A[M][K] @ W[N][K]^T + bias); z-batched via signed strides.

template<int ACT>
__launch_bounds__(256, 3)
__global__ void gemm_main(const bf16* __restrict__ A, long long Az, int lda,
                          const bf16* __restrict__ W, long long Wz,
                          const float* __restrict__ bias, long long bz,
                          bf16* __restrict__ C, long long Cz, int ldc, int K) {
  __shared__ bf16 As[2][128 * 32];
  __shared__ bf16 Bs[2][256 * 32];
  const long long z = blockIdx.z;
  A += z * Az; W += z * Wz; bias += z * bz; C += z * Cz;

  const int tid = threadIdx.x;
  const int lane = tid & 63;
  const int wid = tid >> 6;
  const int brow = blockIdx.x * 128;
  const int bcol = blockIdx.y * 256;
  const int wn = wid * 64;
  const int lr = lane & 15;
  const int kg = lane >> 4;
  const int ko = (kg ^ ((lr >> 1) & 3)) << 3;   // swizzled k-slot (elements)

  f32x4 acc[8][4] = {};

  // staging: thread t -> row t/4, stored slot t&3; source slot pre-inverse-swizzled
  const int scol = (((tid & 3) ^ ((tid >> 3) & 3)) << 3);
  const bf16* Ag = A + (size_t)(brow + (tid >> 2)) * lda + scol;
  const bf16* Wg = W + (size_t)(bcol + (tid >> 2)) * K + scol;

  const int nt = K >> 5;
#define STAGE(buf, k0)                                                        \
  {                                                                           \
    _Pragma("unroll") for (int j = 0; j < 2; ++j)                             \
        gload16(Ag + (size_t)j * 64 * lda + (k0), &As[buf][j * 2048 + wid * 512]); \
    _Pragma("unroll") for (int j = 0; j < 4; ++j)                             \
        gload16(Wg + (size_t)j * 64 * K + (k0), &Bs[buf][j * 2048 + wid * 512]);   \
  }

  STAGE(0, 0)
  for (int t = 0; t < nt; ++t) {
    const int cur = t & 1;
    if (t + 1 < nt) {
      STAGE(cur ^ 1, (t + 1) << 5)
      asm volatile("s_waitcnt vmcnt(6)");   // cur's 6 loads landed; next 6 in flight
    } else {
      asm volatile("s_waitcnt vmcnt(0)");
    }
    __builtin_amdgcn_s_barrier();
    __builtin_amdgcn_sched_barrier(0);
    bf16x8 b[4];
#pragma unroll
    for (int n = 0; n < 4; ++n)
      b[n] = *(const bf16x8*)(&Bs[cur][((wn + n * 16 + lr) << 5) + ko]);
    __builtin_amdgcn_s_setprio(1);
#pragma unroll
    for (int m = 0; m < 8; ++m) {
      bf16x8 a = *(const bf16x8*)(&As[cur][((m * 16 + lr) << 5) + ko]);
#pragma unroll
      for (int n = 0; n < 4; ++n)
        acc[m][n] = __builtin_amdgcn_mfma_f32_16x16x32_bf16(a, b[n], acc[m][n], 0, 0, 0);
    }
    __builtin_amdgcn_s_setprio(0);
    __builtin_amdgcn_sched_barrier(0);
    __builtin_amdgcn_s_barrier();
  }
#undef STAGE

  float bv[4];
#pragma unroll
  for (int n = 0; n < 4; ++n) bv[n] = bias[bcol + wn + n * 16 + lr];
#pragma unroll
  for (int m = 0; m < 8; ++m) {
    int row = brow + m * 16 + kg * 4;
#pragma unroll
    for (int n = 0; n < 4; ++n) {
      int col = bcol + wn + n * 16 + lr;
#pragma unroll
      for (int j = 0; j < 4; ++j) {
        float v = acc[m][n][j] + bv[n];
        if (ACT == 1) v = gelu_fast(v);
        C[(size_t)(row + j) * ldc + col] = (bf16)v;
      }
    }
  }
}

// ---------------------------------------------------------------- fused GEMM + add + LayerNorm
// O = LN(X + A@W^T + bias) * g + b.  N fixed = 512 (full row per block).
// BM=64, BK=32, 8 waves (1Mx8N), dbuf LDS 72KiB -> 2 blocks/CU.

__launch_bounds__(512, 4)
__global__ void gemm_ln(const bf16* __restrict__ A, long long Az, int lda,
                        const bf16* __restrict__ W, long long Wz,
                        const float* __restrict__ bias, long long bz,
                        const bf16* __restrict__ X, long long Xz,
                        const float* __restrict__ g, const float* __restrict__ b, long long gbz,
                        bf16* __restrict__ O, long long Oz, int K) {
  __shared__ bf16 As[2][64 * 32];
  __shared__ bf16 Bs[2][512 * 32];
  const long long z = blockIdx.z;
  A += z * Az; W += z * Wz; bias += z * bz; X += z * Xz; O += z * Oz;
  g += z * gbz; b += z * gbz;

  const int tid = threadIdx.x;
  const int lane = tid & 63;
  const int wid = tid >> 6;
  const int brow = blockIdx.x * 64;
  const int wn = wid * 64;
  const int lr = lane & 15;
  const int kg = lane >> 4;
  const int ko = (kg ^ ((lr >> 1) & 3)) << 3;

  f32x4 acc[4][4] = {};

  // A staged via size-4 loads (all 8 waves): thread t -> row t/16, 4B at (t&15)*4
  const bf16* Ag = A + (size_t)(brow + (tid >> 4)) * lda
                     + (((tid & 15) * 2) ^ (((tid >> 5) & 3) << 3));
  // B staged via size-16 loads: thread t -> row t/4, slot t&3
  const bf16* Wg = W + (size_t)(tid >> 2) * K + (((tid & 3) ^ ((tid >> 3) & 3)) << 3);

  const int nt = K >> 5;
#define STAGE(buf, k0)                                                          \
  {                                                                             \
    _Pragma("unroll") for (int j = 0; j < 2; ++j)                               \
        gload4(Ag + (size_t)j * 32 * lda + (k0), &As[buf][j * 1024 + wid * 128]);    \
    _Pragma("unroll") for (int j = 0; j < 4; ++j)                               \
        gload16(Wg + (size_t)j * 128 * K + (k0), &Bs[buf][j * 4096 + wid * 512]);    \
  }

  STAGE(0, 0)
  for (int t = 0; t < nt; ++t) {
    const int cur = t & 1;
    if (t + 1 < nt) {
      STAGE(cur ^ 1, (t + 1) << 5)
      asm volatile("s_waitcnt vmcnt(6)");
    } else {
      asm volatile("s_waitcnt vmcnt(0)");
    }
    __builtin_amdgcn_s_barrier();
    __builtin_amdgcn_sched_barrier(0);
    bf16x8 bfr[4];
#pragma unroll
    for (int n = 0; n < 4; ++n)
      bfr[n] = *(const bf16x8*)(&Bs[cur][((wn + n * 16 + lr) << 5) + ko]);
    __builtin_amdgcn_s_setprio(1);
#pragma unroll
    for (int m = 0; m < 4; ++m) {
      bf16x8 a = *(const bf16x8*)(&As[cur][((m * 16 + lr) << 5) + ko]);
#pragma unroll
      for (int n = 0; n < 4; ++n)
        acc[m][n] = __builtin_amdgcn_mfma_f32_16x16x32_bf16(a, bfr[n], acc[m][n], 0, 0, 0);
    }
    __builtin_amdgcn_s_setprio(0);
    __builtin_amdgcn_sched_barrier(0);
    __builtin_amdgcn_s_barrier();
  }
#undef STAGE

  // ---- epilogue: bias + residual, row stats, normalize ----
  float bv[4], g4[4], b4[4];
#pragma unroll
  for (int n = 0; n < 4; ++n) {
    int col = wn + n * 16 + lr;
    bv[n] = bias[col]; g4[n] = g[col]; b4[n] = b[col];
  }
  float* fp = (float*)&As[0][0];   // reuse LDS: partials 64x8x2 f32 + stats 64x2 f32

#pragma unroll
  for (int m = 0; m < 4; ++m) {
#pragma unroll
    for (int j = 0; j < 4; ++j) {
      int lrow = m * 16 + kg * 4 + j;
      float s = 0.f, q = 0.f;
#pragma unroll
      for (int n = 0; n < 4; ++n) {
        float v = acc[m][n][j] + bv[n]
                + (float)X[(size_t)(brow + lrow) * 512 + wn + n * 16 + lr];
        acc[m][n][j] = v;
        s += v; q += v * v;
      }
#pragma unroll
      for (int off = 1; off < 16; off <<= 1) {
        s += __shfl_xor(s, off);
        q += __shfl_xor(q, off);
      }
      if (lr == 0) {
        fp[lrow * 8 + wid] = s;
        fp[512 + lrow * 8 + wid] = q;
      }
    }
  }
  __syncthreads();
  if (tid < 64) {
    float s = 0.f, q = 0.f;
#pragma unroll
    for (int w = 0; w < 8; ++w) { s += fp[tid * 8 + w]; q += fp[512 + tid * 8 + w]; }
    float mean = s * (1.f / 512.f);
    float var = q * (1.f / 512.f) - mean * mean;
    fp[1024 + tid * 2] = mean;
    fp[1024 + tid * 2 + 1] = rsqrtf(var + 1e-5f);
  }
  __syncthreads();
#pragma unroll
  for (int m = 0; m < 4; ++m) {
#pragma unroll
    for (int j = 0; j < 4; ++j) {
      int lrow = m * 16 + kg * 4 + j;
      float mean = fp[1024 + lrow * 2];
      float rstd = fp[1024 + lrow * 2 + 1];
#pragma unroll
      for (int n = 0; n < 4; ++n) {
        float v = (acc[m][n][j] - mean) * rstd * g4[n] + b4[n];
        O[(size_t)(brow + lrow) * 512 + wn + n * 16 + lr] = (bf16)v;
      }
    }
  }
}

// ---------------------------------------------------------------- GEMM 128x128 (tiny: Wc)

__launch_bounds__(256)
__global__ void gemm128(const bf16* __restrict__ A, long long Az, int lda,
                        const bf16* __restrict__ W, long long Wz,
                        const float* __restrict__ bias, long long bz,
                        bf16* __restrict__ C, long long Cz, int ldc, int K) {
  __shared__ bf16 As[128 * 64];
  __shared__ bf16 Bs[128 * 64];
  const long long z = blockIdx.z;
  A += z * Az; W += z * Wz; bias += z * bz; C += z * Cz;
  const int tid = threadIdx.x;
  const int lane = tid & 63;
  const int wid = tid >> 6;
  const int brow = blockIdx.x * 128;
  const int bcol = blockIdx.y * 128;
  const int wr = (wid >> 1) * 64;
  const int wc = (wid & 1) * 64;
  const int lr = lane & 15;
  const int kg = lane >> 4;
  f32x4 acc[4][4] = {};
  const bf16* Abase = A + (size_t)(brow + (tid >> 3)) * lda + ((tid & 7) << 3);
  const bf16* Wbase = W + (size_t)(bcol + (tid >> 3)) * K + ((tid & 7) << 3);
  bf16* AsDst = As + wid * 512;
  bf16* BsDst = Bs + wid * 512;
  for (int k0 = 0; k0 < K; k0 += 64) {
#pragma unroll
    for (int j = 0; j < 4; ++j) {
      gload16(Abase + (size_t)j * 32 * lda + k0, AsDst + j * 2048);
      gload16(Wbase + (size_t)j * 32 * K + k0, BsDst + j * 2048);
    }
    __syncthreads();
#pragma unroll
    for (int kk = 0; kk < 64; kk += 32) {
      bf16x8 a[4], bq[4];
#pragma unroll
      for (int m = 0; m < 4; ++m)
        a[m] = *(const bf16x8*)(As + (wr + m * 16 + lr) * 64 + kk + kg * 8);
#pragma unroll
      for (int n = 0; n < 4; ++n)
        bq[n] = *(const bf16x8*)(Bs + (wc + n * 16 + lr) * 64 + kk + kg * 8);
#pragma unroll
      for (int m = 0; m < 4; ++m)
#pragma unroll
        for (int n = 0; n < 4; ++n)
          acc[m][n] = __builtin_amdgcn_mfma_f32_16x16x32_bf16(a[m], bq[n], acc[m][n], 0, 0, 0);
    }
    __syncthreads();
  }
  float bv[4];
#pragma unroll
  for (int n = 0; n < 4; ++n) bv[n] = bias[bcol + wc + n * 16 + lr];
#pragma unroll
  for (int m = 0; m < 4; ++m) {
    int row = brow + wr + m * 16 + kg * 4;
#pragma unroll
    for (int n = 0; n < 4; ++n) {
      int col = bcol + wc + n * 16 + lr;
#pragma unroll
      for (int j = 0; j < 4; ++j)
        C[(size_t)(row + j) * ldc + col] = (bf16)(acc[m][n][j] + bv[n]);
    }
  }
}

// ---------------------------------------------------------------- prior MLP (tiny)

__global__ void prior_fc1(const float* __restrict__ emb, const float* __restrict__ w1,
                          const float* __restrict__ b1, float* __restrict__ h) {
  int j = blockIdx.x * 4 + (threadIdx.x >> 6);
  int lane = threadIdx.x & 63;
  const float* wr = w1 + (size_t)j * 512 + lane * 8;
  const float* e = emb + lane * 8;
  float s = 0.f;
#pragma unroll
  for (int i = 0; i < 8; ++i) s += e[i] * wr[i];
#pragma unroll
  for (int off = 32; off > 0; off >>= 1) s += __shfl_xor(s, off);
  if (lane == 0) h[j] = gelu_exact(s + b1[j]);
}

__global__ void prior_fc2(const float* __restrict__ h, const float* __restrict__ w2,
                          const float* __restrict__ b2, float* __restrict__ p) {
  int j = blockIdx.x * 4 + (threadIdx.x >> 6);
  int lane = threadIdx.x & 63;
  const float* wr = w2 + (size_t)j * 1024 + lane * 16;
  const float* e = h + lane * 16;
  float s = 0.f;
#pragma unroll
  for (int i = 0; i < 16; ++i) s += e[i] * wr[i];
#pragma unroll
  for (int off = 32; off > 0; off >>= 1) s += __shfl_xor(s, off);
  if (lane == 0) p[j] = s + b2[j];
}

// ---------------------------------------------------------------- final select/blend

__global__ void combine(const float* __restrict__ img, const float* __restrict__ txt,
                        const bf16* __restrict__ gen_t, const bf16* __restrict__ gen_i,
                        const float* __restrict__ prior, const int* __restrict__ mt,
                        const float* __restrict__ rw, float* __restrict__ out) {
  int i4 = blockIdx.x * blockDim.x + threadIdx.x;
  if (i4 >= BDIM * 128) return;
  int bb = i4 >> 7;
  int c = (i4 & 127) << 2;
  size_t idx = (size_t)bb * HDIM + c;
  int m = mt[bb];
  f32x4 iv = *(const f32x4*)(img + idx);
  f32x4 tv = *(const f32x4*)(txt + idx);
  f32x4 oi = iv, ot = tv;
  if (m == 2) {
    float r = rw[1];
    bf16x4 gv = *(const bf16x4*)(gen_i + idx);
#pragma unroll
    for (int k = 0; k < 4; ++k) oi[k] = r * iv[k] + (1.f - r) * (float)gv[k];
  } else if (m == 3) {
    oi = *(const f32x4*)(prior + c);
  }
  if (m == 1) {
    float r = rw[0];
    bf16x4 gv = *(const bf16x4*)(gen_t + idx);
#pragma unroll
    for (int k = 0; k < 4; ++k) ot[k] = r * tv[k] + (1.f - r) * (float)gv[k];
  } else if (m == 3) {
    ot = *(const f32x4*)(prior + 512 + c);
  }
  *(f32x4*)(out + idx) = oi;
  *(f32x4*)(out + (size_t)BDIM * HDIM + idx) = ot;
}

// ---------------------------------------------------------------- launch

extern "C" void kernel_launch(void* const* d_in, const int* in_sizes, int n_in,
                              void* d_out, int out_size, void* d_ws, size_t ws_size,
                              hipStream_t stream) {
  const float* img  = (const float*)d_in[0];
  const float* txt  = (const float*)d_in[1];
  const float* ipw  = (const float*)d_in[2];
  const float* ipb  = (const float*)d_in[3];
  const float* qkvw = (const float*)d_in[4];
  const float* qkvb = (const float*)d_in[5];
  const float* aow  = (const float*)d_in[6];
  const float* aob  = (const float*)d_in[7];
  const float* ln1g = (const float*)d_in[8];
  const float* ln1b = (const float*)d_in[9];
  const float* ln2g = (const float*)d_in[10];
  const float* ln2b = (const float*)d_in[11];
  const float* f1w  = (const float*)d_in[12];
  const float* f1b  = (const float*)d_in[13];
  const float* f2w  = (const float*)d_in[14];
  const float* f2b  = (const float*)d_in[15];
  const float* opw  = (const float*)d_in[16];
  const float* opb  = (const float*)d_in[17];
  const float* rw   = (const float*)d_in[18];
  const float* pw1  = (const float*)d_in[19];
  const float* pb1  = (const float*)d_in[20];
  const float* pw2  = (const float*)d_in[21];
  const float* pb2  = (const float*)d_in[22];
  const float* pemb = (const float*)d_in[23];
  const int*   mt   = (const int*)d_in[24];
  float* out = (float*)d_out;

  const size_t B = BDIM;
  char* ws = (char*)d_ws;
  size_t off = 0;
  auto alloc = [&](size_t bytes) -> char* {
    char* p = ws + off;
    off += (bytes + 255) & ~(size_t)255;
    return p;
  };
  bf16* src_bf = (bf16*)alloc(2 * B * 512 * 2);
  bf16* ipw_bf = (bf16*)alloc((size_t)2 * 262144 * 2);
  bf16* wvT_bf = (bf16*)alloc((size_t)6 * 262144 * 2);
  bf16* ao_bf  = (bf16*)alloc((size_t)6 * 262144 * 2);
  bf16* f1_bf  = (bf16*)alloc((size_t)6 * 1048576 * 2);
  bf16* f2_bf  = (bf16*)alloc((size_t)6 * 1048576 * 2);
  bf16* op_bf  = (bf16*)alloc((size_t)2 * 262144 * 2);
  bf16* Wc_bf  = (bf16*)alloc((size_t)6 * 262144 * 2);
  float* bc    = (float*)alloc(6 * 512 * 4);
  float* zeros = (float*)alloc(512 * 4);
  float* ph    = (float*)alloc(1024 * 4);
  float* pout  = (float*)alloc(1024 * 4);
  bf16* x      = (bf16*)alloc(2 * B * 512 * 2);
  bf16* xn     = (bf16*)alloc(2 * B * 512 * 2);

  bool big = (off + (size_t)2 * B * 2048 * 2 + 4096) <= ws_size;
  bf16* h;
  bf16* genb;
  if (big) {
    h = (bf16*)alloc((size_t)2 * B * 2048 * 2);
    genb = h;                        // gens live after h is dead
  } else {
    genb = (bf16*)alloc(2 * B * 512 * 2);
    h = (bf16*)d_out;                // B*2048 bf16; overwritten by combine at end
  }

  auto cvt = [&](const float* s, bf16* d, size_t n) {
    int n4 = (int)(n / 4);
    cvt_f32_bf16<<<(n4 + 255) / 256, 256, 0, stream>>>(s, d, n4);
  };
  cvt(img, src_bf, B * 512);
  cvt(txt, src_bf + B * 512, B * 512);
  cvt(ipw, ipw_bf, 2 * 262144);
  cvt(aow, ao_bf, 6 * 262144);
  cvt(f1w, f1_bf, 6 * 1048576);
  cvt(f2w, f2_bf, 6 * 1048576);
  cvt(opw, op_bf, 2 * 262144);
  cvt_wvT<<<dim3(16, 16, 6), 256, 0, stream>>>(qkvw, wvT_bf);
  zfill<<<2, 256, 0, stream>>>(zeros, 512);
  bias_combine<<<768, 256, 0, stream>>>(aow, qkvb, aob, bc);

  // Wc[il] = ao[il] @ wv[il]
  gemm128<<<dim3(4, 4, 6), 256, 0, stream>>>(ao_bf, 262144, 512, wvT_bf, 262144,
                                             zeros, 0, Wc_bf, 262144, 512, 512);

  const long long BS = (long long)B * 512;
  const long long HS = (long long)B * 2048;

  // x = src @ ipw^T + ipb
  gemm_main<0><<<dim3(128, 2, 2), 256, 0, stream>>>(src_bf, BS, 512, ipw_bf, 262144,
                                                    ipb, 512, x, BS, 512, 512);

  for (int l = 0; l < 3; ++l) {
    // xn = LN1(x + tgt @ Wc_l^T + bc_l)   (tgt: z=0 -> txt, z=1 -> img)
    gemm_ln<<<dim3(256, 1, 2), 512, 0, stream>>>(src_bf + BS, -BS, 512,
                                                 Wc_bf + (size_t)l * 262144, 786432,
                                                 bc + l * 512, 1536, x, BS,
                                                 ln1g + l * 512, ln1b + l * 512, 1536,
                                                 xn, BS, 512);
    if (big) {
      // h = gelu(xn @ f1^T + b1)
      gemm_main<1><<<dim3(128, 8, 2), 256, 0, stream>>>(xn, BS, 512,
                                                        f1_bf + (size_t)l * 1048576, 3145728,
                                                        f1b + l * 2048, 6144, h, HS, 2048, 512);
      // x = LN2(xn + h @ f2^T + b2)
      gemm_ln<<<dim3(256, 1, 2), 512, 0, stream>>>(h, HS, 2048,
                                                   f2_bf + (size_t)l * 1048576, 3145728,
                                                   f2b + l * 512, 1536, xn, BS,
                                                   ln2g + l * 512, ln2b + l * 512, 1536,
                                                   x, BS, 2048);
    } else {
      for (int i = 0; i < 2; ++i) {
        size_t il = (size_t)i * 3 + l;
        gemm_main<1><<<dim3(128, 8, 1), 256, 0, stream>>>(xn + (size_t)i * BS, 0, 512,
                                                          f1_bf + il * 1048576, 0,
                                                          f1b + il * 2048, 0, h, 0, 2048, 512);
        gemm_ln<<<dim3(256, 1, 1), 512, 0, stream>>>(h, 0, 2048,
                                                     f2_bf + il * 1048576, 0,
                                                     f2b + il * 512, 0, xn + (size_t)i * BS, 0,
                                                     ln2g + il * 512, ln2b + il * 512, 0,
                                                     x + (size_t)i * BS, 0, 2048);
      }
    }
  }

  // gen = x @ opw^T + opb
  gemm_main<0><<<dim3(128, 2, 2), 256, 0, stream>>>(x, BS, 512, op_bf, 262144,
                                                    opb, 512, genb, BS, 512, 512);

  prior_fc1<<<256, 256, 0, stream>>>(pemb, pw1, pb1, ph);
  prior_fc2<<<256, 256, 0, stream>>>(ph, pw2, pb2, pout);

  combine<<<(BDIM * 128 + 255) / 256, 256, 0, stream>>>(img, txt, genb, genb + BS,
                                                        pout, mt, rw, out);
}

// Round 4
// 1016.554 us; speedup vs baseline: 1.3407x; 1.1801x over previous
//
#include <hip/hip_runtime.h>
#include <hip/hip_bf16.h>
#include <math.h>

#define BDIM 16384
#define HDIM 512

typedef __bf16 bf16;
typedef float f32x4 __attribute__((ext_vector_type(4)));
typedef __bf16 bf16x8 __attribute__((ext_vector_type(8)));
typedef __bf16 bf16x4 __attribute__((ext_vector_type(4)));

// ---------------------------------------------------------------- utilities

__device__ __forceinline__ void gload16(const bf16* g, bf16* l) {
  __builtin_amdgcn_global_load_lds((const __attribute__((address_space(1))) void*)g,
                                   (__attribute__((address_space(3))) void*)l, 16, 0, 0);
}

__device__ __forceinline__ float gelu_exact(float x) {
  return 0.5f * x * (1.0f + erff(x * 0.70710678118654752f));
}
__device__ __forceinline__ float gelu_fast(float x) {
  float u = x * (0.7978845608f + 0.0356774081f * x * x);
  float e = __expf(2.f * u);
  float t = 1.f - 2.f / (e + 1.f);
  return 0.5f * x * (1.f + t);
}

// ---------------------------------------------------------------- converts

__global__ void cvt_f32_bf16(const float* __restrict__ src, bf16* __restrict__ dst, int n4) {
  int i = blockIdx.x * blockDim.x + threadIdx.x;
  if (i >= n4) return;
  f32x4 v = *(const f32x4*)(src + (size_t)i * 4);
  bf16x4 o;
  o[0] = (bf16)v[0]; o[1] = (bf16)v[1]; o[2] = (bf16)v[2]; o[3] = (bf16)v[3];
  *(bf16x4*)(dst + (size_t)i * 4) = o;
}

// wvT[il][k][m] = wv[il][m][k]; wv = rows 1024..1535 of qkv block il ([1536][512])
__global__ void cvt_wvT(const float* __restrict__ qkv, bf16* __restrict__ dst) {
  __shared__ float t[32][33];
  int il = blockIdx.z;
  int bm = blockIdx.x * 32;
  int bk = blockIdx.y * 32;
  const float* s = qkv + (size_t)il * 786432 + 524288;
  int tx = threadIdx.x & 31, ty = threadIdx.x >> 5;
#pragma unroll
  for (int j = 0; j < 4; ++j)
    t[ty * 4 + j][tx] = s[(size_t)(bm + ty * 4 + j) * 512 + bk + tx];
  __syncthreads();
  bf16* d = dst + (size_t)il * 262144;
#pragma unroll
  for (int j = 0; j < 4; ++j)
    d[(size_t)(bk + ty * 4 + j) * 512 + bm + tx] = (bf16)t[tx][ty * 4 + j];
}

__global__ void zfill(float* __restrict__ p, int n) {
  int i = blockIdx.x * 256 + threadIdx.x;
  if (i < n) p[i] = 0.f;
}

// bc[il][n] = sum_m ao[il][n][m] * bv[il][m] + aob[il][n]
__global__ void bias_combine(const float* __restrict__ aow, const float* __restrict__ qkvb,
                             const float* __restrict__ aob, float* __restrict__ bc) {
  int gid = blockIdx.x * 4 + (threadIdx.x >> 6);
  int il = gid >> 9;
  int lane = threadIdx.x & 63;
  const float* ar = aow + (size_t)gid * 512 + lane * 8;
  const float* bv = qkvb + il * 1536 + 1024 + lane * 8;
  float s = 0.f;
#pragma unroll
  for (int i = 0; i < 8; ++i) s += ar[i] * bv[i];
#pragma unroll
  for (int off = 32; off > 0; off >>= 1) s += __shfl_xor(s, off);
  if (lane == 0) bc[gid] = s + aob[gid];
}

// ---------------------------------------------------------------- main pipelined GEMM
// C[M][N] = act(A[M][K] @ W[N][K]^T + bias [+ X]), 256x256 tile, BK=32,
// 8 waves (2Mx4N), 3-slot LDS ring, prefetch distance 2, counted vmcnt,
// T2 both-sides swizzle, T5 setprio. z-batched via signed strides.

template<int ACT, bool RES, int K>
__launch_bounds__(512, 2)
__global__ void gemm_p(const bf16* __restrict__ A, long long Az,
                       const bf16* __restrict__ W, long long Wz,
                       const float* __restrict__ bias, long long bz,
                       const bf16* __restrict__ X, long long Xz,
                       bf16* __restrict__ C, long long Cz, int ldc) {
  __shared__ bf16 lds[3][2][8192];   // [slot][A/B][256 rows x 32], 96 KiB
  const long long z = blockIdx.z;
  A += z * Az; W += z * Wz; bias += z * bz; C += z * Cz;
  if (RES) X += z * Xz;

  const int tid  = threadIdx.x;
  const int lane = tid & 63;
  const int wid  = tid >> 6;
  const int brow = blockIdx.x * 256;
  const int bcol = blockIdx.y * 256;
  const int wm = (wid >> 2) * 128;   // wave rows: 128
  const int wn = (wid & 3) * 64;     // wave cols: 64
  const int lr = lane & 15;
  const int kg = lane >> 4;
  const int ko = (kg ^ ((lr >> 1) & 3)) << 3;   // swizzled 8-elem k-slot

  f32x4 acc[8][4] = {};

  // staging: thread t -> row t>>2 (within 128-row chunk), stored slot t&3,
  // global source slot pre-inverse-swizzled with the row's bits 1-2.
  const int sco = (((tid & 3) ^ ((tid >> 3) & 3)) << 3);
  const bf16* Ag = A + (size_t)(brow + (tid >> 2)) * K + sco;
  const bf16* Wg = W + (size_t)(bcol + (tid >> 2)) * K + sco;

  auto SA = [&](int s, int kt, int j) {
    gload16(Ag + (size_t)j * 128 * K + kt * 32, &lds[s][0][j * 4096 + wid * 512]);
  };
  auto SB = [&](int s, int kt, int j) {
    gload16(Wg + (size_t)j * 128 * K + kt * 32, &lds[s][1][j * 4096 + wid * 512]);
  };

  const int nt = K / 32;
  // prologue: tiles 0 and 1 (8 loads)
  SA(0, 0, 0); SA(0, 0, 1); SB(0, 0, 0); SB(0, 0, 1);
  SA(1, 1, 0); SA(1, 1, 1); SB(1, 1, 0); SB(1, 1, 1);

  int slot = 0;
  for (int t = 0; t < nt; ++t) {
    int s2 = slot + 2; if (s2 >= 3) s2 -= 3;
    const bf16* ldsA = &lds[slot][0][0];
    const bf16* ldsB = &lds[slot][1][0];
    // ---- phase 0: stage A-units of t+2, wait tile t, MFMA n=0,1 ----
    if (t + 2 < nt) { SA(s2, t + 2, 0); SA(s2, t + 2, 1); }
    if (t + 2 < nt)      asm volatile("s_waitcnt vmcnt(6)" ::: "memory");
    else if (t + 1 < nt) asm volatile("s_waitcnt vmcnt(4)" ::: "memory");
    else                 asm volatile("s_waitcnt vmcnt(0)" ::: "memory");
    __builtin_amdgcn_s_barrier();
    asm volatile("" ::: "memory");
    bf16x8 a[8];
#pragma unroll
    for (int m = 0; m < 8; ++m)
      a[m] = *(const bf16x8*)(ldsA + ((wm + m * 16 + lr) << 5) + ko);
    bf16x8 b0 = *(const bf16x8*)(ldsB + ((wn + 0 * 16 + lr) << 5) + ko);
    bf16x8 b1 = *(const bf16x8*)(ldsB + ((wn + 1 * 16 + lr) << 5) + ko);
    __builtin_amdgcn_s_setprio(1);
#pragma unroll
    for (int m = 0; m < 8; ++m) {
      acc[m][0] = __builtin_amdgcn_mfma_f32_16x16x32_bf16(a[m], b0, acc[m][0], 0, 0, 0);
      acc[m][1] = __builtin_amdgcn_mfma_f32_16x16x32_bf16(a[m], b1, acc[m][1], 0, 0, 0);
    }
    __builtin_amdgcn_s_setprio(0);
    asm volatile("" ::: "memory");
    __builtin_amdgcn_s_barrier();
    // ---- phase 1: stage B-units of t+2, MFMA n=2,3 ----
    if (t + 2 < nt) { SB(s2, t + 2, 0); SB(s2, t + 2, 1); }
    bf16x8 b2 = *(const bf16x8*)(ldsB + ((wn + 2 * 16 + lr) << 5) + ko);
    bf16x8 b3 = *(const bf16x8*)(ldsB + ((wn + 3 * 16 + lr) << 5) + ko);
    __builtin_amdgcn_s_setprio(1);
#pragma unroll
    for (int m = 0; m < 8; ++m) {
      acc[m][2] = __builtin_amdgcn_mfma_f32_16x16x32_bf16(a[m], b2, acc[m][2], 0, 0, 0);
      acc[m][3] = __builtin_amdgcn_mfma_f32_16x16x32_bf16(a[m], b3, acc[m][3], 0, 0, 0);
    }
    __builtin_amdgcn_s_setprio(0);
    asm volatile("" ::: "memory");
    __builtin_amdgcn_s_barrier();   // protects slot before it is restaged
    slot = slot + 1; if (slot >= 3) slot = 0;
  }

  // epilogue: D mapping col=lane&15, row=kg*4+j
  float bv[4];
#pragma unroll
  for (int n = 0; n < 4; ++n) bv[n] = bias[bcol + wn + n * 16 + lr];
#pragma unroll
  for (int m = 0; m < 8; ++m) {
    int row = brow + wm + m * 16 + kg * 4;
#pragma unroll
    for (int n = 0; n < 4; ++n) {
      int col = bcol + wn + n * 16 + lr;
#pragma unroll
      for (int j = 0; j < 4; ++j) {
        float v = acc[m][n][j] + bv[n];
        if (RES) v += (float)X[(size_t)(row + j) * 512 + col];
        if (ACT == 1) v = gelu_fast(v);
        C[(size_t)(row + j) * ldc + col] = (bf16)v;
      }
    }
  }
}

// ---------------------------------------------------------------- GEMM 128x128 (tiny: Wc)

__launch_bounds__(256)
__global__ void gemm128(const bf16* __restrict__ A, long long Az, int lda,
                        const bf16* __restrict__ W, long long Wz,
                        const float* __restrict__ bias, long long bz,
                        bf16* __restrict__ C, long long Cz, int ldc, int K) {
  __shared__ bf16 As[128 * 64];
  __shared__ bf16 Bs[128 * 64];
  const long long z = blockIdx.z;
  A += z * Az; W += z * Wz; bias += z * bz; C += z * Cz;
  const int tid = threadIdx.x;
  const int lane = tid & 63;
  const int wid = tid >> 6;
  const int brow = blockIdx.x * 128;
  const int bcol = blockIdx.y * 128;
  const int wr = (wid >> 1) * 64;
  const int wc = (wid & 1) * 64;
  const int lr = lane & 15;
  const int kg = lane >> 4;
  f32x4 acc[4][4] = {};
  const bf16* Abase = A + (size_t)(brow + (tid >> 3)) * lda + ((tid & 7) << 3);
  const bf16* Wbase = W + (size_t)(bcol + (tid >> 3)) * K + ((tid & 7) << 3);
  bf16* AsDst = As + wid * 512;
  bf16* BsDst = Bs + wid * 512;
  for (int k0 = 0; k0 < K; k0 += 64) {
#pragma unroll
    for (int j = 0; j < 4; ++j) {
      gload16(Abase + (size_t)j * 32 * lda + k0, AsDst + j * 2048);
      gload16(Wbase + (size_t)j * 32 * K + k0, BsDst + j * 2048);
    }
    __syncthreads();
#pragma unroll
    for (int kk = 0; kk < 64; kk += 32) {
      bf16x8 a[4], bq[4];
#pragma unroll
      for (int m = 0; m < 4; ++m)
        a[m] = *(const bf16x8*)(As + (wr + m * 16 + lr) * 64 + kk + kg * 8);
#pragma unroll
      for (int n = 0; n < 4; ++n)
        bq[n] = *(const bf16x8*)(Bs + (wc + n * 16 + lr) * 64 + kk + kg * 8);
#pragma unroll
      for (int m = 0; m < 4; ++m)
#pragma unroll
        for (int n = 0; n < 4; ++n)
          acc[m][n] = __builtin_amdgcn_mfma_f32_16x16x32_bf16(a[m], bq[n], acc[m][n], 0, 0, 0);
    }
    __syncthreads();
  }
  float bv[4];
#pragma unroll
  for (int n = 0; n < 4; ++n) bv[n] = bias[bcol + wc + n * 16 + lr];
#pragma unroll
  for (int m = 0; m < 4; ++m) {
    int row = brow + wr + m * 16 + kg * 4;
#pragma unroll
    for (int n = 0; n < 4; ++n) {
      int col = bcol + wc + n * 16 + lr;
#pragma unroll
      for (int j = 0; j < 4; ++j)
        C[(size_t)(row + j) * ldc + col] = (bf16)(acc[m][n][j] + bv[n]);
    }
  }
}

// ---------------------------------------------------------------- layernorm (rows of 512)
// O = LN(Y) * g + b; gen = row>>14, g/b gen-stride 1536

__global__ void ln_k(const bf16* __restrict__ Y, const float* __restrict__ g,
                     const float* __restrict__ b, bf16* __restrict__ O) {
  int lane = threadIdx.x & 63;
  int row = blockIdx.x * 4 + (threadIdx.x >> 6);
  int gen = row >> 14;
  size_t base = (size_t)row * HDIM + lane * 8;
  bf16x8 yv = *(const bf16x8*)(Y + base);
  float v[8], s = 0.f, q = 0.f;
#pragma unroll
  for (int i = 0; i < 8; ++i) {
    v[i] = (float)yv[i];
    s += v[i]; q += v[i] * v[i];
  }
#pragma unroll
  for (int off = 32; off > 0; off >>= 1) {
    s += __shfl_xor(s, off);
    q += __shfl_xor(q, off);
  }
  float mean = s * (1.f / HDIM);
  float var = q * (1.f / HDIM) - mean * mean;
  float rstd = rsqrtf(var + 1e-5f);
  const float* gp = g + gen * 1536 + lane * 8;
  const float* bp = b + gen * 1536 + lane * 8;
  bf16x8 o;
#pragma unroll
  for (int i = 0; i < 8; ++i) o[i] = (bf16)((v[i] - mean) * rstd * gp[i] + bp[i]);
  *(bf16x8*)(O + base) = o;
}

// ---------------------------------------------------------------- prior MLP (tiny)

__global__ void prior_fc1(const float* __restrict__ emb, const float* __restrict__ w1,
                          const float* __restrict__ b1, float* __restrict__ h) {
  int j = blockIdx.x * 4 + (threadIdx.x >> 6);
  int lane = threadIdx.x & 63;
  const float* wr = w1 + (size_t)j * 512 + lane * 8;
  const float* e = emb + lane * 8;
  float s = 0.f;
#pragma unroll
  for (int i = 0; i < 8; ++i) s += e[i] * wr[i];
#pragma unroll
  for (int off = 32; off > 0; off >>= 1) s += __shfl_xor(s, off);
  if (lane == 0) h[j] = gelu_exact(s + b1[j]);
}

__global__ void prior_fc2(const float* __restrict__ h, const float* __restrict__ w2,
                          const float* __restrict__ b2, float* __restrict__ p) {
  int j = blockIdx.x * 4 + (threadIdx.x >> 6);
  int lane = threadIdx.x & 63;
  const float* wr = w2 + (size_t)j * 1024 + lane * 16;
  const float* e = h + lane * 16;
  float s = 0.f;
#pragma unroll
  for (int i = 0; i < 16; ++i) s += e[i] * wr[i];
#pragma unroll
  for (int off = 32; off > 0; off >>= 1) s += __shfl_xor(s, off);
  if (lane == 0) p[j] = s + b2[j];
}

// ---------------------------------------------------------------- final select/blend

__global__ void combine(const float* __restrict__ img, const float* __restrict__ txt,
                        const bf16* __restrict__ gen_t, const bf16* __restrict__ gen_i,
                        const float* __restrict__ prior, const int* __restrict__ mt,
                        const float* __restrict__ rw, float* __restrict__ out) {
  int i4 = blockIdx.x * blockDim.x + threadIdx.x;
  if (i4 >= BDIM * 128) return;
  int bb = i4 >> 7;
  int c = (i4 & 127) << 2;
  size_t idx = (size_t)bb * HDIM + c;
  int m = mt[bb];
  f32x4 iv = *(const f32x4*)(img + idx);
  f32x4 tv = *(const f32x4*)(txt + idx);
  f32x4 oi = iv, ot = tv;
  if (m == 2) {
    float r = rw[1];
    bf16x4 gv = *(const bf16x4*)(gen_i + idx);
#pragma unroll
    for (int k = 0; k < 4; ++k) oi[k] = r * iv[k] + (1.f - r) * (float)gv[k];
  } else if (m == 3) {
    oi = *(const f32x4*)(prior + c);
  }
  if (m == 1) {
    float r = rw[0];
    bf16x4 gv = *(const bf16x4*)(gen_t + idx);
#pragma unroll
    for (int k = 0; k < 4; ++k) ot[k] = r * tv[k] + (1.f - r) * (float)gv[k];
  } else if (m == 3) {
    ot = *(const f32x4*)(prior + 512 + c);
  }
  *(f32x4*)(out + idx) = oi;
  *(f32x4*)(out + (size_t)BDIM * HDIM + idx) = ot;
}

// ---------------------------------------------------------------- launch

extern "C" void kernel_launch(void* const* d_in, const int* in_sizes, int n_in,
                              void* d_out, int out_size, void* d_ws, size_t ws_size,
                              hipStream_t stream) {
  const float* img  = (const float*)d_in[0];
  const float* txt  = (const float*)d_in[1];
  const float* ipw  = (const float*)d_in[2];
  const float* ipb  = (const float*)d_in[3];
  const float* qkvw = (const float*)d_in[4];
  const float* qkvb = (const float*)d_in[5];
  const float* aow  = (const float*)d_in[6];
  const float* aob  = (const float*)d_in[7];
  const float* ln1g = (const float*)d_in[8];
  const float* ln1b = (const float*)d_in[9];
  const float* ln2g = (const float*)d_in[10];
  const float* ln2b = (const float*)d_in[11];
  const float* f1w  = (const float*)d_in[12];
  const float* f1b  = (const float*)d_in[13];
  const float* f2w  = (const float*)d_in[14];
  const float* f2b  = (const float*)d_in[15];
  const float* opw  = (const float*)d_in[16];
  const float* opb  = (const float*)d_in[17];
  const float* rw   = (const float*)d_in[18];
  const float* pw1  = (const float*)d_in[19];
  const float* pb1  = (const float*)d_in[20];
  const float* pw2  = (const float*)d_in[21];
  const float* pb2  = (const float*)d_in[22];
  const float* pemb = (const float*)d_in[23];
  const int*   mt   = (const int*)d_in[24];
  float* out = (float*)d_out;

  const size_t B = BDIM;
  char* ws = (char*)d_ws;
  size_t off = 0;
  auto alloc = [&](size_t bytes) -> char* {
    char* p = ws + off;
    off += (bytes + 255) & ~(size_t)255;
    return p;
  };
  bf16* src_bf = (bf16*)alloc(2 * B * 512 * 2);
  bf16* ipw_bf = (bf16*)alloc((size_t)2 * 262144 * 2);
  bf16* wvT_bf = (bf16*)alloc((size_t)6 * 262144 * 2);
  bf16* ao_bf  = (bf16*)alloc((size_t)6 * 262144 * 2);
  bf16* f1_bf  = (bf16*)alloc((size_t)6 * 1048576 * 2);
  bf16* f2_bf  = (bf16*)alloc((size_t)6 * 1048576 * 2);
  bf16* op_bf  = (bf16*)alloc((size_t)2 * 262144 * 2);
  bf16* Wc_bf  = (bf16*)alloc((size_t)6 * 262144 * 2);
  float* bc    = (float*)alloc(6 * 512 * 4);
  float* zeros = (float*)alloc(512 * 4);
  float* ph    = (float*)alloc(1024 * 4);
  float* pout  = (float*)alloc(1024 * 4);
  bf16* x      = (bf16*)alloc(2 * B * 512 * 2);
  bf16* xn     = (bf16*)alloc(2 * B * 512 * 2);
  bf16* sbuf   = (bf16*)alloc(2 * B * 512 * 2);
  bf16* genb   = sbuf;   // gen outputs reuse sbuf (dead by then)

  bool big = (off + (size_t)2 * B * 2048 * 2 + 4096) <= ws_size;
  bf16* h = big ? (bf16*)alloc((size_t)2 * B * 2048 * 2)
                : (bf16*)d_out;   // fallback: one gen's h fits d_out exactly

  auto cvt = [&](const float* s, bf16* d, size_t n) {
    int n4 = (int)(n / 4);
    cvt_f32_bf16<<<(n4 + 255) / 256, 256, 0, stream>>>(s, d, n4);
  };
  cvt(img, src_bf, B * 512);
  cvt(txt, src_bf + B * 512, B * 512);
  cvt(ipw, ipw_bf, 2 * 262144);
  cvt(aow, ao_bf, 6 * 262144);
  cvt(f1w, f1_bf, 6 * 1048576);
  cvt(f2w, f2_bf, 6 * 1048576);
  cvt(opw, op_bf, 2 * 262144);
  cvt_wvT<<<dim3(16, 16, 6), 256, 0, stream>>>(qkvw, wvT_bf);
  zfill<<<2, 256, 0, stream>>>(zeros, 512);
  bias_combine<<<768, 256, 0, stream>>>(aow, qkvb, aob, bc);

  // Wc[il] = ao[il] @ wv[il]
  gemm128<<<dim3(4, 4, 6), 256, 0, stream>>>(ao_bf, 262144, 512, wvT_bf, 262144,
                                             zeros, 0, Wc_bf, 262144, 512, 512);

  const long long BS = (long long)B * 512;
  const long long HS = (long long)B * 2048;

  // x = src @ ipw^T + ipb
  gemm_p<0, false, 512><<<dim3(64, 2, 2), 512, 0, stream>>>(
      src_bf, BS, ipw_bf, 262144, ipb, 512, nullptr, 0, x, BS, 512);

  for (int l = 0; l < 3; ++l) {
    // sbuf = x + tgt @ Wc_l^T + bc_l   (tgt: z=0 -> txt, z=1 -> img)
    gemm_p<0, true, 512><<<dim3(64, 2, 2), 512, 0, stream>>>(
        src_bf + BS, -BS, Wc_bf + (size_t)l * 262144, 786432,
        bc + l * 512, 1536, x, BS, sbuf, BS, 512);
    ln_k<<<2 * BDIM / 4, 256, 0, stream>>>(sbuf, ln1g + l * 512, ln1b + l * 512, xn);
    if (big) {
      // h = gelu(xn @ f1^T + b1)
      gemm_p<1, false, 512><<<dim3(64, 8, 2), 512, 0, stream>>>(
          xn, BS, f1_bf + (size_t)l * 1048576, 3145728,
          f1b + l * 2048, 6144, nullptr, 0, h, HS, 2048);
      // sbuf = xn + h @ f2^T + b2
      gemm_p<0, true, 2048><<<dim3(64, 2, 2), 512, 0, stream>>>(
          h, HS, f2_bf + (size_t)l * 1048576, 3145728,
          f2b + l * 512, 1536, xn, BS, sbuf, BS, 512);
    } else {
      for (int i = 0; i < 2; ++i) {
        size_t il = (size_t)i * 3 + l;
        gemm_p<1, false, 512><<<dim3(64, 8, 1), 512, 0, stream>>>(
            xn + (size_t)i * BS, 0, f1_bf + il * 1048576, 0,
            f1b + il * 2048, 0, nullptr, 0, h, 0, 2048);
        gemm_p<0, true, 2048><<<dim3(64, 2, 1), 512, 0, stream>>>(
            h, 0, f2_bf + il * 1048576, 0,
            f2b + il * 512, 0, xn + (size_t)i * BS, 0, sbuf + (size_t)i * BS, 0, 512);
      }
    }
    ln_k<<<2 * BDIM / 4, 256, 0, stream>>>(sbuf, ln2g + l * 512, ln2b + l * 512, x);
  }

  // gen = x @ opw^T + opb  (z=0 -> gen_text, z=1 -> gen_img); overwrites sbuf
  gemm_p<0, false, 512><<<dim3(64, 2, 2), 512, 0, stream>>>(
      x, BS, op_bf, 262144, opb, 512, nullptr, 0, genb, BS, 512);

  prior_fc1<<<256, 256, 0, stream>>>(pemb, pw1, pb1, ph);
  prior_fc2<<<256, 256, 0, stream>>>(ph, pw2, pb2, pout);

  combine<<<(BDIM * 128 + 255) / 256, 256, 0, stream>>>(img, txt, genb, genb + BS,
                                                        pout, mt, rw, out);
}